// Round 8
// baseline (1906.864 us; speedup 1.0000x reference)
//
#include <hip/hip_runtime.h>
#include <hip/hip_cooperative_groups.h>

// Problem: B=128, S=256, V=50000, E=512, H=1024, O=10
// R14 = R11 (best, 1210us) + ONE mechanism change: fully DISTRIBUTED
// per-wave producer-consumer sync replacing the central epoch barrier.
// (R12/R13's gx tiling + counted-vmcnt are REVERTED — R13 disproved the
// drain-exposure theory; R11 layout is empirically best.)
// Mechanism: wave w of block cg only consumes h cols [w*256,(w+1)*256),
// produced by blocks w*16..w*16+15 (all 4 waves each). So: 256 epoch
// slots per rs-group (one PER WAVE, 16B stride). Tail: h sc1-store ->
// s_waitcnt vmcnt(0) (own stores LLC-acked) -> lane0 stores s+2 to my
// wave slot. Head: poll MY 64 producer-wave slots (one per lane) for
// >= s+1, then load h. No entry/release __syncthreads, no central
// detector, wait set 64->16 blocks, h-loads start on LOCAL readiness.
// Intra-block: pre4 double-buffered -> ONE __syncthreads per step
// (write->read join; 2-buffer + loop-barrier induction = race-free).
// All else identical R11: L2-cached h loads, 16-buffer h rotation,
// amortized acquire fence at s%16==0, sc1 h stores, R11 gx layout.

typedef __attribute__((ext_vector_type(8))) _Float16 half8;
typedef __attribute__((ext_vector_type(4))) float f32x4;

#define MFMA16(a, b, c) __builtin_amdgcn_mfma_f32_16x16x32_f16((a), (b), (c), 0, 0, 0)

__device__ __forceinline__ float sigm(float x) { return 1.0f / (1.0f + __expf(-x)); }
__device__ __forceinline__ float tanh_(float x) { return 1.0f - 2.0f / (__expf(2.0f * x) + 1.0f); }

// ---------------- cast / gather kernels (R11 exact) ----------------

__global__ __launch_bounds__(256) void k_cast_e(const int* __restrict__ x,
                                                const float* __restrict__ emb,
                                                _Float16* __restrict__ e) {
  int idx = (blockIdx.x * 256 + threadIdx.x) * 8;  // < 16777216
  int m = idx >> 9, k = idx & 511;
  int tok = x[m];
  const float* src = emb + (long)tok * 512 + k;
  float4 a = *(const float4*)src;
  float4 b = *(const float4*)(src + 4);
  half8 h;
  h[0] = (_Float16)a.x; h[1] = (_Float16)a.y; h[2] = (_Float16)a.z; h[3] = (_Float16)a.w;
  h[4] = (_Float16)b.x; h[5] = (_Float16)b.y; h[6] = (_Float16)b.z; h[7] = (_Float16)b.w;
  *(half8*)(e + idx) = h;
}

__global__ __launch_bounds__(256) void k_cast_wi(const float* __restrict__ Wii, const float* __restrict__ Wif,
                                                 const float* __restrict__ Wig, const float* __restrict__ Wio,
                                                 _Float16* __restrict__ Wi) {
  int idx = (blockIdx.x * 256 + threadIdx.x) * 8;  // < 2097152
  int g = idx >> 19;
  const float* src = (g == 0) ? Wii : (g == 1) ? Wif : (g == 2) ? Wig : Wio;
  src += idx & 524287;
  float4 a = *(const float4*)src;
  float4 b = *(const float4*)(src + 4);
  half8 h;
  h[0] = (_Float16)a.x; h[1] = (_Float16)a.y; h[2] = (_Float16)a.z; h[3] = (_Float16)a.w;
  h[4] = (_Float16)b.x; h[5] = (_Float16)b.y; h[6] = (_Float16)b.z; h[7] = (_Float16)b.w;
  *(half8*)(Wi + idx) = h;
}

// Wh_f16[n'][k], n' = cg*64 + g*16 + cc  (h-col = cg*16+cc), k<1024
__global__ __launch_bounds__(256) void k_cast_wh(const float* __restrict__ Whi, const float* __restrict__ Whf,
                                                 const float* __restrict__ Whg, const float* __restrict__ Who,
                                                 _Float16* __restrict__ Wh) {
  int idx = (blockIdx.x * 256 + threadIdx.x) * 8;  // < 4194304
  int n = idx >> 10, k = idx & 1023;
  int cg = n >> 6, rem = n & 63, g = rem >> 4, cc = rem & 15;
  const float* src = (g == 0) ? Whi : (g == 1) ? Whf : (g == 2) ? Whg : Who;
  src += (cg * 16 + cc) * 1024 + k;
  float4 a = *(const float4*)src;
  float4 b = *(const float4*)(src + 4);
  half8 h;
  h[0] = (_Float16)a.x; h[1] = (_Float16)a.y; h[2] = (_Float16)a.z; h[3] = (_Float16)a.w;
  h[4] = (_Float16)b.x; h[5] = (_Float16)b.y; h[6] = (_Float16)b.z; h[7] = (_Float16)b.w;
  *(half8*)(Wh + idx) = h;
}

__global__ __launch_bounds__(256) void k_cast_bias(const float* __restrict__ bii, const float* __restrict__ bif,
                                                   const float* __restrict__ big, const float* __restrict__ bio,
                                                   float* __restrict__ bc) {
  int n = blockIdx.x * 256 + threadIdx.x;  // < 4096
  int g = n >> 10, hh = n & 1023;
  const float* src = (g == 0) ? bii : (g == 1) ? bif : (g == 2) ? big : bio;
  bc[n] = src[hh];
}

__global__ void k_zero(unsigned int* p) { p[blockIdx.x * 256 + threadIdx.x] = 0u; }

// ---------------- GEMM1: gx[s][g][b][h] = e @ Wi^T + bias (R11 exact) ----------------
__global__ __launch_bounds__(256) void k_gemm1(const _Float16* __restrict__ E, const _Float16* __restrict__ Wi,
                                               const float* __restrict__ bias, _Float16* __restrict__ gx) {
  __shared__ _Float16 As[128][40];
  __shared__ _Float16 Bs[128][40];
  const int t = threadIdx.x;
  const int bm = blockIdx.x >> 5, bn = blockIdx.x & 31;
  const int m0 = bm << 7, n0 = bn << 7;
  const int lane = t & 63, wv = t >> 6;
  const int wm = (wv >> 1) << 6, wn = (wv & 1) << 6;
  const int ln = lane & 15, q = lane >> 4;
  const int rowA0 = t >> 2, kc0 = t & 3;
  const int rowA1 = (t + 256) >> 2, kc1 = (t + 256) & 3;

  f32x4 acc[4][4] = {};

  for (int k0 = 0; k0 < 512; k0 += 32) {
    *(half8*)&As[rowA0][kc0 * 8] = *(const half8*)(E + (m0 + rowA0) * 512 + k0 + kc0 * 8);
    *(half8*)&As[rowA1][kc1 * 8] = *(const half8*)(E + (m0 + rowA1) * 512 + k0 + kc1 * 8);
    *(half8*)&Bs[rowA0][kc0 * 8] = *(const half8*)(Wi + (n0 + rowA0) * 512 + k0 + kc0 * 8);
    *(half8*)&Bs[rowA1][kc1 * 8] = *(const half8*)(Wi + (n0 + rowA1) * 512 + k0 + kc1 * 8);
    __syncthreads();
    half8 af[4], bf[4];
#pragma unroll
    for (int i = 0; i < 4; i++) af[i] = *(const half8*)&As[wm + i * 16 + ln][q * 8];
#pragma unroll
    for (int i = 0; i < 4; i++) bf[i] = *(const half8*)&Bs[wn + i * 16 + ln][q * 8];
#pragma unroll
    for (int mi = 0; mi < 4; mi++)
#pragma unroll
      for (int ni = 0; ni < 4; ni++) acc[mi][ni] = MFMA16(af[mi], bf[ni], acc[mi][ni]);
    __syncthreads();
  }

#pragma unroll
  for (int ni = 0; ni < 4; ni++) {
    int n = n0 + wn + ni * 16 + ln;
    float bv = bias[n];
    int g = n >> 10, hh = n & 1023;
#pragma unroll
    for (int mi = 0; mi < 4; mi++) {
#pragma unroll
      for (int r = 0; r < 4; r++) {
        int m = m0 + wm + mi * 16 + q * 4 + r;
        int b = m >> 8, s = m & 255;
        float v = acc[mi][ni][r] + bv;
        gx[(long)(((s << 2) | g) * 128 + b) * 1024 + hh] = (_Float16)v;
      }
    }
  }
}

// ---------------- LSTM scan: distributed per-wave sync ----------------
__global__ __launch_bounds__(256, 1) void k_lstm(const _Float16* __restrict__ gx, const _Float16* __restrict__ Wh,
                                                 _Float16* __restrict__ hrot, float* __restrict__ hT,
                                                 unsigned int* __restrict__ bar) {
  // double-buffered [step&1][wave][gate][row][col] partials: 69,632 B
  __shared__ float pre4[2][4][4][32][17];
  const int bid = blockIdx.x;
  const int cg = bid & 63, rs = bid >> 6;
  const int r0 = rs << 5, c0 = cg << 4;
  const int t = threadIdx.x, lane = t & 63, w = t >> 6;
  const int ln = lane & 15, q = lane >> 4;
  unsigned int* grp = bar + rs * 1024;  // 4 KB per rs-group: 256 wave-slots x 16 B
  // my arrival slot (per wave); this lane's producer slot:
  // producer block w*16 + (lane>>2), producer wave lane&3
  unsigned int* myslot = grp + ((cg << 2) + w) * 4;
  unsigned int* pslot = grp + ((((w << 4) + (lane >> 2)) << 2) + (lane & 3)) * 4;

  // B-fragments for ALL 4 gates over this wave's K-quarter (R11 form)
  half8 breg[4][8];
  const _Float16* wbase = Wh + (cg * 64 + ln) * 1024 + w * 256 + q * 8;
#pragma unroll
  for (int g = 0; g < 4; g++)
#pragma unroll
    for (int ks = 0; ks < 8; ks++)
      breg[g][ks] = *(const half8*)(wbase + g * 16 * 1024 + ks * 32);

  const int e0 = t << 1;
  const int erow = e0 >> 4, ecol = e0 & 15;
  // zero our slice of h buffer 0 (sc1 write-through: LLC-visible to all XCDs).
  // Wave w's threads cover rows w*8..w*8+7 of this block's 32x16 slice.
  __hip_atomic_store((unsigned int*)(hrot + (r0 + erow) * 1024 + c0 + ecol), 0u,
                     __ATOMIC_RELAXED, __HIP_MEMORY_SCOPE_AGENT);
  // own zero-stores LLC-acked (wave-level vmcnt), then arrive epoch 1
  asm volatile("s_waitcnt vmcnt(0)" ::: "memory");
  if (lane == 0)
    __hip_atomic_store(myslot, 1u, __ATOMIC_RELAXED, __HIP_MEMORY_SCOPE_AGENT);
  asm volatile("" ::: "memory");

  // prefetch gx for s=0 (gate w; R11 scattered form)
  float nx[2][4];
  {
    const _Float16* gp = gx + (long)((0 * 4 + w) * 128 + r0) * 1024 + c0 + ln;
#pragma unroll
    for (int mi = 0; mi < 2; mi++)
#pragma unroll
      for (int r = 0; r < 4; r++) nx[mi][r] = (float)gp[(mi * 16 + q * 4 + r) * 1024];
  }

  float cst0 = 0.f, cst1 = 0.f;

  for (int s = 0; s < 256; s++) {
    // ---- distributed wait: MY 16 producer blocks (x4 waves) at epoch >= s+1.
    // One slot per lane; wave proceeds on LOCAL readiness, not global max.
    {
      const unsigned int target = (unsigned int)(s + 1);
      for (;;) {
        unsigned int v = __hip_atomic_load(pslot, __ATOMIC_RELAXED, __HIP_MEMORY_SCOPE_AGENT);
        if (__all(v >= target)) break;
        __builtin_amdgcn_s_sleep(1);
      }
    }
    // fence compiler hoists: h loads must not move above the poll (rule #18)
    __builtin_amdgcn_sched_barrier(0);
    asm volatile("" ::: "memory");
    // Amortized acquire: invalidate L1/L2 once per 16 steps (buffer reuse
    // period = 16 steps; exactly one fence in every 16-step span before reuse).
    if ((s & 15) == 0) __builtin_amdgcn_fence(__ATOMIC_ACQUIRE, "agent");

    const _Float16* hcur = hrot + (s & 15) * 131072;
    _Float16* hnxt = hrot + ((s + 1) & 15) * 131072;

    // ---- h loads for this wave's K-quarter: PLAIN cached dwordx4 loads (L2).
    half8 ha0[8], ha1[8];
    const _Float16* arow0 = hcur + (r0 + ln) * 1024 + w * 256 + q * 8;
    const _Float16* arow1 = arow0 + 16 * 1024;  // +16 rows
#pragma unroll
    for (int ks = 0; ks < 8; ks++) {
      ha0[ks] = *(const half8*)(arow0 + ks * 32);
      ha1[ks] = *(const half8*)(arow1 + ks * 32);
    }

    // partial accumulators: [gate][m-tile]; owner wave folds its gx in
    f32x4 acc[4][2];
#pragma unroll
    for (int g = 0; g < 4; g++)
#pragma unroll
      for (int mi = 0; mi < 2; mi++)
#pragma unroll
        for (int r = 0; r < 4; r++) acc[g][mi][r] = (g == w) ? nx[mi][r] : 0.f;

    // prefetch next step's gx (hidden under this step's MFMAs; R11 form)
    {
      int sp = (s < 255) ? s + 1 : 255;
      const _Float16* gp = gx + (long)((sp * 4 + w) * 128 + r0) * 1024 + c0 + ln;
#pragma unroll
      for (int mi = 0; mi < 2; mi++)
#pragma unroll
        for (int r = 0; r < 4; r++) nx[mi][r] = (float)gp[(mi * 16 + q * 4 + r) * 1024];
    }

    // MFMA loop: 8 ks x 4 gates x 2 m-tiles = 64 MFMAs, 8 independent chains
#pragma unroll
    for (int ks = 0; ks < 8; ks++) {
#pragma unroll
      for (int g = 0; g < 4; g++) {
        acc[g][0] = MFMA16(ha0[ks], breg[g][ks], acc[g][0]);
        acc[g][1] = MFMA16(ha1[ks], breg[g][ks], acc[g][1]);
      }
    }

    // write K-quarter partials for all 4 gates (double-buffered)
    const int sb = s & 1;
#pragma unroll
    for (int g = 0; g < 4; g++)
#pragma unroll
      for (int mi = 0; mi < 2; mi++)
#pragma unroll
        for (int r = 0; r < 4; r++)
          pre4[sb][w][g][mi * 16 + q * 4 + r][ln] = acc[g][mi][r];
    __syncthreads();  // the ONLY intra-block barrier per step (write->read join)

    // consumer: full pre-activation = sum of 4 wave partials per gate
    float sg[4][2];
#pragma unroll
    for (int g = 0; g < 4; g++) {
      float a = 0.f, b = 0.f;
#pragma unroll
      for (int ww = 0; ww < 4; ww++) {
        a += pre4[sb][ww][g][erow][ecol];
        b += pre4[sb][ww][g][erow][ecol + 1];
      }
      sg[g][0] = a; sg[g][1] = b;
    }
    float i0 = sigm(sg[0][0]), f0 = sigm(sg[1][0]), g0 = tanh_(sg[2][0]), o0 = sigm(sg[3][0]);
    float i1 = sigm(sg[0][1]), f1 = sigm(sg[1][1]), g1 = tanh_(sg[2][1]), o1 = sigm(sg[3][1]);
    cst0 = f0 * cst0 + i0 * g0;
    cst1 = f1 * cst1 + i1 * g1;
    float h0 = o0 * tanh_(cst0);
    float h1 = o1 * tanh_(cst1);
    union { _Float16 h[2]; unsigned int u; } pk;
    pk.h[0] = (_Float16)h0; pk.h[1] = (_Float16)h1;

    if (s == 255) {
      float* hp = hT + (r0 + erow) * 1024 + c0 + ecol;
      hp[0] = h0; hp[1] = h1;
    } else {
      // sc1 write-through store: LLC-visible, bypasses L2
      __hip_atomic_store((unsigned int*)(hnxt + (r0 + erow) * 1024 + c0 + ecol), pk.u,
                         __ATOMIC_RELAXED, __HIP_MEMORY_SCOPE_AGENT);
      // own h-stores LLC-acked before arrival (wave-level vmcnt drain)
      asm volatile("s_waitcnt vmcnt(0)" ::: "memory");
      if (lane == 0)
        __hip_atomic_store(myslot, (unsigned int)(s + 2), __ATOMIC_RELAXED,
                           __HIP_MEMORY_SCOPE_AGENT);
      asm volatile("" ::: "memory");
    }
  }
}

// ---------------- final FC (exact fp32) ----------------
__global__ __launch_bounds__(256) void k_fc(const float* __restrict__ hT, const float* __restrict__ W,
                                            const float* __restrict__ bias, float* __restrict__ out) {
  int gid = blockIdx.x * 4 + (threadIdx.x >> 6);  // wave id < 1280
  int lane = threadIdx.x & 63;
  int b = gid / 10, o = gid - b * 10;
  const float* hp = hT + b * 1024;
  const float* wp = W + o * 1024;
  float sum = 0.f;
  for (int k = lane; k < 1024; k += 64) sum += hp[k] * wp[k];
#pragma unroll
  for (int off = 32; off > 0; off >>= 1) sum += __shfl_down(sum, off, 64);
  if (lane == 0) out[b * 10 + o] = sum + bias[o];
}

// ---------------- launch ----------------
extern "C" void kernel_launch(void* const* d_in, const int* in_sizes, int n_in,
                              void* d_out, int out_size, void* d_ws, size_t ws_size,
                              hipStream_t stream) {
  const int* x = (const int*)d_in[0];
  const float* emb = (const float*)d_in[1];
  const float* Wii = (const float*)d_in[2];
  const float* bii = (const float*)d_in[3];
  const float* Whi = (const float*)d_in[4];
  const float* Wif = (const float*)d_in[5];
  const float* bif = (const float*)d_in[6];
  const float* Whf = (const float*)d_in[7];
  const float* Wig = (const float*)d_in[8];
  const float* big = (const float*)d_in[9];
  const float* Whg = (const float*)d_in[10];
  const float* Wio = (const float*)d_in[11];
  const float* bio = (const float*)d_in[12];
  const float* Who = (const float*)d_in[13];
  const float* fcW = (const float*)d_in[14];
  const float* fcb = (const float*)d_in[15];

  char* ws = (char*)d_ws;
  _Float16* gx = (_Float16*)ws;                    // 268,435,456 B
  _Float16* E = (_Float16*)(ws + 268435456);       // 33,554,432 B (dead after gemm1)
  _Float16* hrot = (_Float16*)(ws + 268435456);    // 4,194,304 B  (16 x 256 KB, overlays E)
  _Float16* WiB = (_Float16*)(ws + 301989888);     // 4,194,304 B
  _Float16* WhB = (_Float16*)(ws + 306184192);     // 8,388,608 B
  float* biasC = (float*)(ws + 314572800);         // 16,384 B
  float* hT = (float*)(ws + 315113472);            // 524,288 B
  unsigned int* bar = (unsigned int*)(ws + 315637760);  // 16,384 B (total ~316 MB)
  float* out = (float*)d_out;

  k_cast_e<<<8192, 256, 0, stream>>>(x, emb, E);
  k_cast_wi<<<1024, 256, 0, stream>>>(Wii, Wif, Wig, Wio, WiB);
  k_cast_wh<<<2048, 256, 0, stream>>>(Whi, Whf, Whg, Who, WhB);
  k_cast_bias<<<16, 256, 0, stream>>>(bii, bif, big, bio, biasC);
  k_gemm1<<<8192, 256, 0, stream>>>(E, WiB, biasC, gx);
  k_zero<<<16, 256, 0, stream>>>(bar);

  const _Float16* gx_a = gx;
  const _Float16* wh_a = WhB;
  _Float16* hb_a = hrot;
  float* ht_a = hT;
  unsigned int* bar_a = bar;
  void* kargs[] = {(void*)&gx_a, (void*)&wh_a, (void*)&hb_a, (void*)&ht_a, (void*)&bar_a};
  hipLaunchCooperativeKernel(k_lstm, dim3(256), dim3(256), kargs, 0, stream);

  k_fc<<<320, 256, 0, stream>>>(hT, fcW, fcb, out);
}

// Round 9
// 1766.104 us; speedup vs baseline: 1.0797x; 1.0797x over previous
//
#include <hip/hip_runtime.h>
#include <hip/hip_cooperative_groups.h>

// Problem: B=128, S=256, V=50000, E=512, H=1024, O=10
// R15 = R11 (best, 1210us) with ONE mechanism change: gx prefetch moved into
// the SYNC SHADOW + raw-barrier release. R11 issued the gx prefetch before
// the MFMA loop; it then crossed TWO __syncthreads (mid-step pre4 join +
// gsync entry), each emitting s_waitcnt vmcnt(0) -> the scattered-HBM
// prefetch tail (~0.4-1us) was drained inside a barrier and max-amplified
// across the 64-block group. (R13 seemed to test this but was confounded by
// the tiled-gx layout; R14's distributed sync also coupled arrival to the
// prefetch via per-wave vmcnt(0) and regressed.) New tail:
//   h sc1-store -> __syncthreads (drains ONLY the h-store; nothing else
//   outstanding) -> issue gx prefetch(s+1) -> wave0 slot-arrival + 64-slot
//   parallel poll (prefetch completes under this ~1us window) -> release
//   via RAW s_barrier (asm, no vmcnt drain -- LDS ordering already sealed
//   by the entry sync; next-step h-loads can't issue before release).
// nx kept as raw _Float16 regs, converted at acc-init (no VALU on the
// load path). All else byte-identical R11: L2-cached h loads, 16-buffer
// rotation, amortized acquire fence at s%16==0, central epoch-slot
// barrier, sc1 h stores, R11 gx layout.

typedef __attribute__((ext_vector_type(8))) _Float16 half8;
typedef __attribute__((ext_vector_type(4))) float f32x4;

#define MFMA16(a, b, c) __builtin_amdgcn_mfma_f32_16x16x32_f16((a), (b), (c), 0, 0, 0)

__device__ __forceinline__ float sigm(float x) { return 1.0f / (1.0f + __expf(-x)); }
__device__ __forceinline__ float tanh_(float x) { return 1.0f - 2.0f / (__expf(2.0f * x) + 1.0f); }

// ---------------- cast / gather kernels (R11 exact) ----------------

__global__ __launch_bounds__(256) void k_cast_e(const int* __restrict__ x,
                                                const float* __restrict__ emb,
                                                _Float16* __restrict__ e) {
  int idx = (blockIdx.x * 256 + threadIdx.x) * 8;  // < 16777216
  int m = idx >> 9, k = idx & 511;
  int tok = x[m];
  const float* src = emb + (long)tok * 512 + k;
  float4 a = *(const float4*)src;
  float4 b = *(const float4*)(src + 4);
  half8 h;
  h[0] = (_Float16)a.x; h[1] = (_Float16)a.y; h[2] = (_Float16)a.z; h[3] = (_Float16)a.w;
  h[4] = (_Float16)b.x; h[5] = (_Float16)b.y; h[6] = (_Float16)b.z; h[7] = (_Float16)b.w;
  *(half8*)(e + idx) = h;
}

__global__ __launch_bounds__(256) void k_cast_wi(const float* __restrict__ Wii, const float* __restrict__ Wif,
                                                 const float* __restrict__ Wig, const float* __restrict__ Wio,
                                                 _Float16* __restrict__ Wi) {
  int idx = (blockIdx.x * 256 + threadIdx.x) * 8;  // < 2097152
  int g = idx >> 19;
  const float* src = (g == 0) ? Wii : (g == 1) ? Wif : (g == 2) ? Wig : Wio;
  src += idx & 524287;
  float4 a = *(const float4*)src;
  float4 b = *(const float4*)(src + 4);
  half8 h;
  h[0] = (_Float16)a.x; h[1] = (_Float16)a.y; h[2] = (_Float16)a.z; h[3] = (_Float16)a.w;
  h[4] = (_Float16)b.x; h[5] = (_Float16)b.y; h[6] = (_Float16)b.z; h[7] = (_Float16)b.w;
  *(half8*)(Wi + idx) = h;
}

// Wh_f16[n'][k], n' = cg*64 + g*16 + cc  (h-col = cg*16+cc), k<1024
__global__ __launch_bounds__(256) void k_cast_wh(const float* __restrict__ Whi, const float* __restrict__ Whf,
                                                 const float* __restrict__ Whg, const float* __restrict__ Who,
                                                 _Float16* __restrict__ Wh) {
  int idx = (blockIdx.x * 256 + threadIdx.x) * 8;  // < 4194304
  int n = idx >> 10, k = idx & 1023;
  int cg = n >> 6, rem = n & 63, g = rem >> 4, cc = rem & 15;
  const float* src = (g == 0) ? Whi : (g == 1) ? Whf : (g == 2) ? Whg : Who;
  src += (cg * 16 + cc) * 1024 + k;
  float4 a = *(const float4*)src;
  float4 b = *(const float4*)(src + 4);
  half8 h;
  h[0] = (_Float16)a.x; h[1] = (_Float16)a.y; h[2] = (_Float16)a.z; h[3] = (_Float16)a.w;
  h[4] = (_Float16)b.x; h[5] = (_Float16)b.y; h[6] = (_Float16)b.z; h[7] = (_Float16)b.w;
  *(half8*)(Wh + idx) = h;
}

__global__ __launch_bounds__(256) void k_cast_bias(const float* __restrict__ bii, const float* __restrict__ bif,
                                                   const float* __restrict__ big, const float* __restrict__ bio,
                                                   float* __restrict__ bc) {
  int n = blockIdx.x * 256 + threadIdx.x;  // < 4096
  int g = n >> 10, hh = n & 1023;
  const float* src = (g == 0) ? bii : (g == 1) ? bif : (g == 2) ? big : bio;
  bc[n] = src[hh];
}

__global__ void k_zero(unsigned int* p) { p[blockIdx.x * 256 + threadIdx.x] = 0u; }

// ---------------- GEMM1: gx[s][g][b][h] = e @ Wi^T + bias (R11 exact) ----------------
__global__ __launch_bounds__(256) void k_gemm1(const _Float16* __restrict__ E, const _Float16* __restrict__ Wi,
                                               const float* __restrict__ bias, _Float16* __restrict__ gx) {
  __shared__ _Float16 As[128][40];
  __shared__ _Float16 Bs[128][40];
  const int t = threadIdx.x;
  const int bm = blockIdx.x >> 5, bn = blockIdx.x & 31;
  const int m0 = bm << 7, n0 = bn << 7;
  const int lane = t & 63, wv = t >> 6;
  const int wm = (wv >> 1) << 6, wn = (wv & 1) << 6;
  const int ln = lane & 15, q = lane >> 4;
  const int rowA0 = t >> 2, kc0 = t & 3;
  const int rowA1 = (t + 256) >> 2, kc1 = (t + 256) & 3;

  f32x4 acc[4][4] = {};

  for (int k0 = 0; k0 < 512; k0 += 32) {
    *(half8*)&As[rowA0][kc0 * 8] = *(const half8*)(E + (m0 + rowA0) * 512 + k0 + kc0 * 8);
    *(half8*)&As[rowA1][kc1 * 8] = *(const half8*)(E + (m0 + rowA1) * 512 + k0 + kc1 * 8);
    *(half8*)&Bs[rowA0][kc0 * 8] = *(const half8*)(Wi + (n0 + rowA0) * 512 + k0 + kc0 * 8);
    *(half8*)&Bs[rowA1][kc1 * 8] = *(const half8*)(Wi + (n0 + rowA1) * 512 + k0 + kc1 * 8);
    __syncthreads();
    half8 af[4], bf[4];
#pragma unroll
    for (int i = 0; i < 4; i++) af[i] = *(const half8*)&As[wm + i * 16 + ln][q * 8];
#pragma unroll
    for (int i = 0; i < 4; i++) bf[i] = *(const half8*)&Bs[wn + i * 16 + ln][q * 8];
#pragma unroll
    for (int mi = 0; mi < 4; mi++)
#pragma unroll
      for (int ni = 0; ni < 4; ni++) acc[mi][ni] = MFMA16(af[mi], bf[ni], acc[mi][ni]);
    __syncthreads();
  }

#pragma unroll
  for (int ni = 0; ni < 4; ni++) {
    int n = n0 + wn + ni * 16 + ln;
    float bv = bias[n];
    int g = n >> 10, hh = n & 1023;
#pragma unroll
    for (int mi = 0; mi < 4; mi++) {
#pragma unroll
      for (int r = 0; r < 4; r++) {
        int m = m0 + wm + mi * 16 + q * 4 + r;
        int b = m >> 8, s = m & 255;
        float v = acc[mi][ni][r] + bv;
        gx[(long)(((s << 2) | g) * 128 + b) * 1024 + hh] = (_Float16)v;
      }
    }
  }
}

// ---------------- pre-loop barrier (R11 exact full form) ----------------
__device__ __forceinline__ void gsync(unsigned int* grp, int cg, int lane, int w,
                                      unsigned int epoch) {
  __syncthreads();
  if (w == 0) {
    if (lane == 0)
      __hip_atomic_store(grp + cg * 16, epoch, __ATOMIC_RELAXED, __HIP_MEMORY_SCOPE_AGENT);
    for (;;) {
      unsigned int v = __hip_atomic_load(grp + lane * 16, __ATOMIC_RELAXED,
                                         __HIP_MEMORY_SCOPE_AGENT);
      if (__all(v >= epoch)) break;
      __builtin_amdgcn_s_sleep(1);
    }
  }
  __syncthreads();
}

// ---------------- LSTM scan: K-split waves, sync-shadow prefetch ----------------
__global__ __launch_bounds__(256, 1) void k_lstm(const _Float16* __restrict__ gx, const _Float16* __restrict__ Wh,
                                                 _Float16* __restrict__ hrot, float* __restrict__ hT,
                                                 unsigned int* __restrict__ bar) {
  // [wave][gate][row][col]: per-wave K-quarter partial pre-activations
  __shared__ float pre4[4][4][32][17];  // 34,816 B
  const int bid = blockIdx.x;
  const int cg = bid & 63, rs = bid >> 6;
  const int r0 = rs << 5, c0 = cg << 4;
  const int t = threadIdx.x, lane = t & 63, w = t >> 6;
  const int ln = lane & 15, q = lane >> 4;
  unsigned int* grp = bar + rs * 1024;  // 4 KB per group: 64 slots x 64 B

  // B-fragments for ALL 4 gates over this wave's K-quarter:
  // rows cg*64 + g*16 + ln, k = w*256 + ks*32 + q*8 .. +7, ks = 0..7
  half8 breg[4][8];
  const _Float16* wbase = Wh + (cg * 64 + ln) * 1024 + w * 256 + q * 8;
#pragma unroll
  for (int g = 0; g < 4; g++)
#pragma unroll
    for (int ks = 0; ks < 8; ks++)
      breg[g][ks] = *(const half8*)(wbase + g * 16 * 1024 + ks * 32);

  const int e0 = t << 1;
  const int erow = e0 >> 4, ecol = e0 & 15;
  // zero our slice of h buffer 0 (sc1 write-through: LLC-visible to all XCDs)
  __hip_atomic_store((unsigned int*)(hrot + (r0 + erow) * 1024 + c0 + ecol), 0u,
                     __ATOMIC_RELAXED, __HIP_MEMORY_SCOPE_AGENT);

  float cst0 = 0.f, cst1 = 0.f;
  unsigned int ep = 1;
  gsync(grp, cg, lane, w, ep); ep++;

  // prefetch gx for s=0 (raw f16 regs; converted at acc-init; completes
  // under the first h-load burst)
  _Float16 nxh[2][4];
  {
    const _Float16* gp = gx + (long)((0 * 4 + w) * 128 + r0) * 1024 + c0 + ln;
#pragma unroll
    for (int mi = 0; mi < 2; mi++)
#pragma unroll
      for (int r = 0; r < 4; r++) nxh[mi][r] = gp[(mi * 16 + q * 4 + r) * 1024];
  }

  for (int s = 0; s < 256; s++) {
    // Amortized acquire: invalidate L1/L2 once per 16 steps (buffer reuse
    // period = 16 steps; exactly one fence in every 16-step span before reuse).
    if ((s & 15) == 0) __builtin_amdgcn_fence(__ATOMIC_ACQUIRE, "agent");

    const _Float16* hcur = hrot + (s & 15) * 131072;
    _Float16* hnxt = hrot + ((s + 1) & 15) * 131072;

    // ---- h loads for this wave's K-quarter: PLAIN cached dwordx4 loads (L2).
    half8 ha0[8], ha1[8];
    const _Float16* arow0 = hcur + (r0 + ln) * 1024 + w * 256 + q * 8;
    const _Float16* arow1 = arow0 + 16 * 1024;  // +16 rows
#pragma unroll
    for (int ks = 0; ks < 8; ks++) {
      ha0[ks] = *(const half8*)(arow0 + ks * 32);
      ha1[ks] = *(const half8*)(arow1 + ks * 32);
    }

    // partial accumulators: [gate][m-tile]; owner wave folds its gx in
    // (nxh was prefetched in the PREVIOUS step's sync shadow — complete by now)
    f32x4 acc[4][2];
#pragma unroll
    for (int g = 0; g < 4; g++)
#pragma unroll
      for (int mi = 0; mi < 2; mi++)
#pragma unroll
        for (int r = 0; r < 4; r++) acc[g][mi][r] = (g == w) ? (float)nxh[mi][r] : 0.f;

    // MFMA loop: 8 ks x 4 gates x 2 m-tiles = 64 MFMAs, 8 independent chains.
    // NOTE: no VMEM issued between here and the tail -> the mid-step and
    // entry syncs drain nothing but the h-store (the R11 exposure is gone).
#pragma unroll
    for (int ks = 0; ks < 8; ks++) {
#pragma unroll
      for (int g = 0; g < 4; g++) {
        acc[g][0] = MFMA16(ha0[ks], breg[g][ks], acc[g][0]);
        acc[g][1] = MFMA16(ha1[ks], breg[g][ks], acc[g][1]);
      }
    }

    // write K-quarter partials for all 4 gates
#pragma unroll
    for (int g = 0; g < 4; g++)
#pragma unroll
      for (int mi = 0; mi < 2; mi++)
#pragma unroll
        for (int r = 0; r < 4; r++)
          pre4[w][g][mi * 16 + q * 4 + r][ln] = acc[g][mi][r];
    __syncthreads();

    // consumer: full pre-activation = sum of 4 wave partials per gate
    float sg[4][2];
#pragma unroll
    for (int g = 0; g < 4; g++) {
      float a = 0.f, b = 0.f;
#pragma unroll
      for (int ww = 0; ww < 4; ww++) {
        a += pre4[ww][g][erow][ecol];
        b += pre4[ww][g][erow][ecol + 1];
      }
      sg[g][0] = a; sg[g][1] = b;
    }
    float i0 = sigm(sg[0][0]), f0 = sigm(sg[1][0]), g0 = tanh_(sg[2][0]), o0 = sigm(sg[3][0]);
    float i1 = sigm(sg[0][1]), f1 = sigm(sg[1][1]), g1 = tanh_(sg[2][1]), o1 = sigm(sg[3][1]);
    cst0 = f0 * cst0 + i0 * g0;
    cst1 = f1 * cst1 + i1 * g1;
    float h0 = o0 * tanh_(cst0);
    float h1 = o1 * tanh_(cst1);
    union { _Float16 h[2]; unsigned int u; } pk;
    pk.h[0] = (_Float16)h0; pk.h[1] = (_Float16)h1;

    if (s == 255) {
      float* hp = hT + (r0 + erow) * 1024 + c0 + ecol;
      hp[0] = h0; hp[1] = h1;
    } else {
      // sc1 write-through store: LLC-visible, bypasses L2
      __hip_atomic_store((unsigned int*)(hnxt + (r0 + erow) * 1024 + c0 + ecol), pk.u,
                         __ATOMIC_RELAXED, __HIP_MEMORY_SCOPE_AGENT);
      // entry: per-wave vmcnt(0) drains ONLY the h-store; barrier release
      // implies all 4 waves' h-stores are LLC-acked -> flag store is safe.
      __syncthreads();
      // gx prefetch for s+1: issued IN the sync shadow; rides through the
      // poll and the raw release barrier (no vmcnt drain touches it), and
      // completes under poll + next step's h-load burst.
      {
        const _Float16* gp = gx + (long)(((s + 1) * 4 + w) * 128 + r0) * 1024 + c0 + ln;
#pragma unroll
        for (int mi = 0; mi < 2; mi++)
#pragma unroll
          for (int r = 0; r < 4; r++) nxh[mi][r] = gp[(mi * 16 + q * 4 + r) * 1024];
      }
      if (w == 0) {
        if (lane == 0)
          __hip_atomic_store(grp + cg * 16, ep, __ATOMIC_RELAXED, __HIP_MEMORY_SCOPE_AGENT);
        for (;;) {
          unsigned int v = __hip_atomic_load(grp + lane * 16, __ATOMIC_RELAXED,
                                             __HIP_MEMORY_SCOPE_AGENT);
          if (__all(v >= ep)) break;
          __builtin_amdgcn_s_sleep(1);
        }
      }
      // raw release: NO vmcnt drain (LDS ordering sealed by the entry sync;
      // next-step h-loads cannot issue before barrier release).
      asm volatile("s_barrier" ::: "memory");
      ep++;
    }
  }
}

// ---------------- final FC (exact fp32) ----------------
__global__ __launch_bounds__(256) void k_fc(const float* __restrict__ hT, const float* __restrict__ W,
                                            const float* __restrict__ bias, float* __restrict__ out) {
  int gid = blockIdx.x * 4 + (threadIdx.x >> 6);  // wave id < 1280
  int lane = threadIdx.x & 63;
  int b = gid / 10, o = gid - b * 10;
  const float* hp = hT + b * 1024;
  const float* wp = W + o * 1024;
  float sum = 0.f;
  for (int k = lane; k < 1024; k += 64) sum += hp[k] * wp[k];
#pragma unroll
  for (int off = 32; off > 0; off >>= 1) sum += __shfl_down(sum, off, 64);
  if (lane == 0) out[b * 10 + o] = sum + bias[o];
}

// ---------------- launch ----------------
extern "C" void kernel_launch(void* const* d_in, const int* in_sizes, int n_in,
                              void* d_out, int out_size, void* d_ws, size_t ws_size,
                              hipStream_t stream) {
  const int* x = (const int*)d_in[0];
  const float* emb = (const float*)d_in[1];
  const float* Wii = (const float*)d_in[2];
  const float* bii = (const float*)d_in[3];
  const float* Whi = (const float*)d_in[4];
  const float* Wif = (const float*)d_in[5];
  const float* bif = (const float*)d_in[6];
  const float* Whf = (const float*)d_in[7];
  const float* Wig = (const float*)d_in[8];
  const float* big = (const float*)d_in[9];
  const float* Whg = (const float*)d_in[10];
  const float* Wio = (const float*)d_in[11];
  const float* bio = (const float*)d_in[12];
  const float* Who = (const float*)d_in[13];
  const float* fcW = (const float*)d_in[14];
  const float* fcb = (const float*)d_in[15];

  char* ws = (char*)d_ws;
  _Float16* gx = (_Float16*)ws;                    // 268,435,456 B
  _Float16* E = (_Float16*)(ws + 268435456);       // 33,554,432 B (dead after gemm1)
  _Float16* hrot = (_Float16*)(ws + 268435456);    // 4,194,304 B  (16 x 256 KB, overlays E)
  _Float16* WiB = (_Float16*)(ws + 301989888);     // 4,194,304 B
  _Float16* WhB = (_Float16*)(ws + 306184192);     // 8,388,608 B
  float* biasC = (float*)(ws + 314572800);         // 16,384 B
  float* hT = (float*)(ws + 315113472);            // 524,288 B
  unsigned int* bar = (unsigned int*)(ws + 315637760);  // 16,384 B (total ~316 MB)
  float* out = (float*)d_out;

  k_cast_e<<<8192, 256, 0, stream>>>(x, emb, E);
  k_cast_wi<<<1024, 256, 0, stream>>>(Wii, Wif, Wig, Wio, WiB);
  k_cast_wh<<<2048, 256, 0, stream>>>(Whi, Whf, Whg, Who, WhB);
  k_cast_bias<<<16, 256, 0, stream>>>(bii, bif, big, bio, biasC);
  k_gemm1<<<8192, 256, 0, stream>>>(E, WiB, biasC, gx);
  k_zero<<<16, 256, 0, stream>>>(bar);

  const _Float16* gx_a = gx;
  const _Float16* wh_a = WhB;
  _Float16* hb_a = hrot;
  float* ht_a = hT;
  unsigned int* bar_a = bar;
  void* kargs[] = {(void*)&gx_a, (void*)&wh_a, (void*)&hb_a, (void*)&ht_a, (void*)&bar_a};
  hipLaunchCooperativeKernel(k_lstm, dim3(256), dim3(256), kargs, 0, stream);

  k_fc<<<320, 256, 0, stream>>>(hT, fcW, fcb, out);
}

// Round 10
// 1558.169 us; speedup vs baseline: 1.2238x; 1.1334x over previous
//
#include <hip/hip_runtime.h>
#include <hip/hip_cooperative_groups.h>

// Problem: B=128, S=256, V=50000, E=512, H=1024, O=10
// R16 = R11 with ONE mechanism change: distributed PER-WAVE WAIT with
// PER-BLOCK arrival. R14/R15 post-mortems isolated a shared flaw (scattered
// gx HBM loads outstanding at a vmcnt(0) gating arrival/poll -> arrival or
// release delayed by the HBM tail, amplified group-wide). This version:
//  - tail: h sc1-store -> __syncthreads (drains ONLY h-stores) -> t==0
//    stores the block's arrival slot (R11 slot geometry, 1 store/block) ->
//    THEN issue the gx prefetch (its drain can only self-delay our own next
//    poll, which overlaps producer-wait anyway).
//  - head: wave w polls ONLY its 16 producer blocks' slots (cols
//    [w*256,(w+1)*256) come from blocks cg'=w*16..w*16+15); on success the
//    wave starts its h loads immediately -- no release barrier hop, wait
//    fan-in 64 -> 16 blocks.
//  - intra-block: single pre4 buffer, mid-step __syncthreads (producer
//    write -> consumer read) + entry __syncthreads; next-step pre4 writes
//    happen after own poll > entry sync, so no double buffer needed.
// All else identical R11: L2-cached h loads, 16-buffer h rotation,
// amortized per-wave acquire fence at s%16==0 (after poll, before loads),
// sc1 h stores, R11 gx layout, breg in AGPRs.

typedef __attribute__((ext_vector_type(8))) _Float16 half8;
typedef __attribute__((ext_vector_type(4))) float f32x4;

#define MFMA16(a, b, c) __builtin_amdgcn_mfma_f32_16x16x32_f16((a), (b), (c), 0, 0, 0)

__device__ __forceinline__ float sigm(float x) { return 1.0f / (1.0f + __expf(-x)); }
__device__ __forceinline__ float tanh_(float x) { return 1.0f - 2.0f / (__expf(2.0f * x) + 1.0f); }

// ---------------- cast / gather kernels (R11 exact) ----------------

__global__ __launch_bounds__(256) void k_cast_e(const int* __restrict__ x,
                                                const float* __restrict__ emb,
                                                _Float16* __restrict__ e) {
  int idx = (blockIdx.x * 256 + threadIdx.x) * 8;  // < 16777216
  int m = idx >> 9, k = idx & 511;
  int tok = x[m];
  const float* src = emb + (long)tok * 512 + k;
  float4 a = *(const float4*)src;
  float4 b = *(const float4*)(src + 4);
  half8 h;
  h[0] = (_Float16)a.x; h[1] = (_Float16)a.y; h[2] = (_Float16)a.z; h[3] = (_Float16)a.w;
  h[4] = (_Float16)b.x; h[5] = (_Float16)b.y; h[6] = (_Float16)b.z; h[7] = (_Float16)b.w;
  *(half8*)(e + idx) = h;
}

__global__ __launch_bounds__(256) void k_cast_wi(const float* __restrict__ Wii, const float* __restrict__ Wif,
                                                 const float* __restrict__ Wig, const float* __restrict__ Wio,
                                                 _Float16* __restrict__ Wi) {
  int idx = (blockIdx.x * 256 + threadIdx.x) * 8;  // < 2097152
  int g = idx >> 19;
  const float* src = (g == 0) ? Wii : (g == 1) ? Wif : (g == 2) ? Wig : Wio;
  src += idx & 524287;
  float4 a = *(const float4*)src;
  float4 b = *(const float4*)(src + 4);
  half8 h;
  h[0] = (_Float16)a.x; h[1] = (_Float16)a.y; h[2] = (_Float16)a.z; h[3] = (_Float16)a.w;
  h[4] = (_Float16)b.x; h[5] = (_Float16)b.y; h[6] = (_Float16)b.z; h[7] = (_Float16)b.w;
  *(half8*)(Wi + idx) = h;
}

// Wh_f16[n'][k], n' = cg*64 + g*16 + cc  (h-col = cg*16+cc), k<1024
__global__ __launch_bounds__(256) void k_cast_wh(const float* __restrict__ Whi, const float* __restrict__ Whf,
                                                 const float* __restrict__ Whg, const float* __restrict__ Who,
                                                 _Float16* __restrict__ Wh) {
  int idx = (blockIdx.x * 256 + threadIdx.x) * 8;  // < 4194304
  int n = idx >> 10, k = idx & 1023;
  int cg = n >> 6, rem = n & 63, g = rem >> 4, cc = rem & 15;
  const float* src = (g == 0) ? Whi : (g == 1) ? Whf : (g == 2) ? Whg : Who;
  src += (cg * 16 + cc) * 1024 + k;
  float4 a = *(const float4*)src;
  float4 b = *(const float4*)(src + 4);
  half8 h;
  h[0] = (_Float16)a.x; h[1] = (_Float16)a.y; h[2] = (_Float16)a.z; h[3] = (_Float16)a.w;
  h[4] = (_Float16)b.x; h[5] = (_Float16)b.y; h[6] = (_Float16)b.z; h[7] = (_Float16)b.w;
  *(half8*)(Wh + idx) = h;
}

__global__ __launch_bounds__(256) void k_cast_bias(const float* __restrict__ bii, const float* __restrict__ bif,
                                                   const float* __restrict__ big, const float* __restrict__ bio,
                                                   float* __restrict__ bc) {
  int n = blockIdx.x * 256 + threadIdx.x;  // < 4096
  int g = n >> 10, hh = n & 1023;
  const float* src = (g == 0) ? bii : (g == 1) ? bif : (g == 2) ? big : bio;
  bc[n] = src[hh];
}

__global__ void k_zero(unsigned int* p) { p[blockIdx.x * 256 + threadIdx.x] = 0u; }

// ---------------- GEMM1: gx[s][g][b][h] = e @ Wi^T + bias (R11 exact) ----------------
__global__ __launch_bounds__(256) void k_gemm1(const _Float16* __restrict__ E, const _Float16* __restrict__ Wi,
                                               const float* __restrict__ bias, _Float16* __restrict__ gx) {
  __shared__ _Float16 As[128][40];
  __shared__ _Float16 Bs[128][40];
  const int t = threadIdx.x;
  const int bm = blockIdx.x >> 5, bn = blockIdx.x & 31;
  const int m0 = bm << 7, n0 = bn << 7;
  const int lane = t & 63, wv = t >> 6;
  const int wm = (wv >> 1) << 6, wn = (wv & 1) << 6;
  const int ln = lane & 15, q = lane >> 4;
  const int rowA0 = t >> 2, kc0 = t & 3;
  const int rowA1 = (t + 256) >> 2, kc1 = (t + 256) & 3;

  f32x4 acc[4][4] = {};

  for (int k0 = 0; k0 < 512; k0 += 32) {
    *(half8*)&As[rowA0][kc0 * 8] = *(const half8*)(E + (m0 + rowA0) * 512 + k0 + kc0 * 8);
    *(half8*)&As[rowA1][kc1 * 8] = *(const half8*)(E + (m0 + rowA1) * 512 + k0 + kc1 * 8);
    *(half8*)&Bs[rowA0][kc0 * 8] = *(const half8*)(Wi + (n0 + rowA0) * 512 + k0 + kc0 * 8);
    *(half8*)&Bs[rowA1][kc1 * 8] = *(const half8*)(Wi + (n0 + rowA1) * 512 + k0 + kc1 * 8);
    __syncthreads();
    half8 af[4], bf[4];
#pragma unroll
    for (int i = 0; i < 4; i++) af[i] = *(const half8*)&As[wm + i * 16 + ln][q * 8];
#pragma unroll
    for (int i = 0; i < 4; i++) bf[i] = *(const half8*)&Bs[wn + i * 16 + ln][q * 8];
#pragma unroll
    for (int mi = 0; mi < 4; mi++)
#pragma unroll
      for (int ni = 0; ni < 4; ni++) acc[mi][ni] = MFMA16(af[mi], bf[ni], acc[mi][ni]);
    __syncthreads();
  }

#pragma unroll
  for (int ni = 0; ni < 4; ni++) {
    int n = n0 + wn + ni * 16 + ln;
    float bv = bias[n];
    int g = n >> 10, hh = n & 1023;
#pragma unroll
    for (int mi = 0; mi < 4; mi++) {
#pragma unroll
      for (int r = 0; r < 4; r++) {
        int m = m0 + wm + mi * 16 + q * 4 + r;
        int b = m >> 8, s = m & 255;
        float v = acc[mi][ni][r] + bv;
        gx[(long)(((s << 2) | g) * 128 + b) * 1024 + hh] = (_Float16)v;
      }
    }
  }
}

// ---------------- LSTM scan: per-wave wait, per-block arrival ----------------
__global__ __launch_bounds__(256, 1) void k_lstm(const _Float16* __restrict__ gx, const _Float16* __restrict__ Wh,
                                                 _Float16* __restrict__ hrot, float* __restrict__ hT,
                                                 unsigned int* __restrict__ bar) {
  // [wave][gate][row][col]: per-wave K-quarter partial pre-activations
  __shared__ float pre4[4][4][32][17];  // 34,816 B
  const int bid = blockIdx.x;
  const int cg = bid & 63, rs = bid >> 6;
  const int r0 = rs << 5, c0 = cg << 4;
  const int t = threadIdx.x, lane = t & 63, w = t >> 6;
  const int ln = lane & 15, q = lane >> 4;
  unsigned int* grp = bar + rs * 1024;  // 4 KB per group: 64 slots x 64 B
  unsigned int* myslot = grp + cg * 16;
  // wave w's producers: blocks cg' = w*16 .. w*16+15 (cols w*256..w*256+255)
  unsigned int* pslot = grp + ((w << 4) + (lane & 15)) * 16;

  // B-fragments for ALL 4 gates over this wave's K-quarter (AGPR-resident):
  half8 breg[4][8];
  const _Float16* wbase = Wh + (cg * 64 + ln) * 1024 + w * 256 + q * 8;
#pragma unroll
  for (int g = 0; g < 4; g++)
#pragma unroll
    for (int ks = 0; ks < 8; ks++)
      breg[g][ks] = *(const half8*)(wbase + g * 16 * 1024 + ks * 32);

  const int e0 = t << 1;
  const int erow = e0 >> 4, ecol = e0 & 15;
  // zero our slice of h buffer 0 (sc1 write-through: LLC-visible to all XCDs)
  __hip_atomic_store((unsigned int*)(hrot + (r0 + erow) * 1024 + c0 + ecol), 0u,
                     __ATOMIC_RELAXED, __HIP_MEMORY_SCOPE_AGENT);
  __syncthreads();  // drains every wave's zero-stores (vmcnt(0) at barrier)
  if (t == 0)
    __hip_atomic_store(myslot, 1u, __ATOMIC_RELAXED, __HIP_MEMORY_SCOPE_AGENT);

  // prefetch gx for s=0 (raw f16 regs; converted at acc-init)
  _Float16 nxh[2][4];
  {
    const _Float16* gp = gx + (long)((0 * 4 + w) * 128 + r0) * 1024 + c0 + ln;
#pragma unroll
    for (int mi = 0; mi < 2; mi++)
#pragma unroll
      for (int r = 0; r < 4; r++) nxh[mi][r] = gp[(mi * 16 + q * 4 + r) * 1024];
  }

  float cst0 = 0.f, cst1 = 0.f;

  for (int s = 0; s < 256; s++) {
    // ---- per-wave wait: MY 16 producer blocks at epoch >= s+1.
    // (first poll read may drain our own gx prefetch -- self-delay only,
    // overlapped with waiting for producers.)
    {
      const unsigned int target = (unsigned int)(s + 1);
      for (;;) {
        unsigned int v = __hip_atomic_load(pslot, __ATOMIC_RELAXED, __HIP_MEMORY_SCOPE_AGENT);
        if (__all(v >= target)) break;
        __builtin_amdgcn_s_sleep(1);
      }
    }
    // keep h loads below the poll (rule #18)
    __builtin_amdgcn_sched_barrier(0);
    asm volatile("" ::: "memory");
    // Amortized acquire (per wave, after ITS poll): invalidate L1/L2 once per
    // 16 steps; buffer addresses reuse only every 16 steps, and every 16-step
    // span contains exactly one fence before reuse.
    if ((s & 15) == 0) __builtin_amdgcn_fence(__ATOMIC_ACQUIRE, "agent");

    const _Float16* hcur = hrot + (s & 15) * 131072;
    _Float16* hnxt = hrot + ((s + 1) & 15) * 131072;

    // ---- h loads for this wave's K-quarter: PLAIN cached dwordx4 loads (L2).
    half8 ha0[8], ha1[8];
    const _Float16* arow0 = hcur + (r0 + ln) * 1024 + w * 256 + q * 8;
    const _Float16* arow1 = arow0 + 16 * 1024;  // +16 rows
#pragma unroll
    for (int ks = 0; ks < 8; ks++) {
      ha0[ks] = *(const half8*)(arow0 + ks * 32);
      ha1[ks] = *(const half8*)(arow1 + ks * 32);
    }

    // partial accumulators: [gate][m-tile]; owner wave folds its gx in
    f32x4 acc[4][2];
#pragma unroll
    for (int g = 0; g < 4; g++)
#pragma unroll
      for (int mi = 0; mi < 2; mi++)
#pragma unroll
        for (int r = 0; r < 4; r++) acc[g][mi][r] = (g == w) ? (float)nxh[mi][r] : 0.f;

    // MFMA loop: 8 ks x 4 gates x 2 m-tiles = 64 MFMAs, 8 independent chains
#pragma unroll
    for (int ks = 0; ks < 8; ks++) {
#pragma unroll
      for (int g = 0; g < 4; g++) {
        acc[g][0] = MFMA16(ha0[ks], breg[g][ks], acc[g][0]);
        acc[g][1] = MFMA16(ha1[ks], breg[g][ks], acc[g][1]);
      }
    }

    // write K-quarter partials for all 4 gates
#pragma unroll
    for (int g = 0; g < 4; g++)
#pragma unroll
      for (int mi = 0; mi < 2; mi++)
#pragma unroll
        for (int r = 0; r < 4; r++)
          pre4[w][g][mi * 16 + q * 4 + r][ln] = acc[g][mi][r];
    __syncthreads();  // mid-step join: producers -> consumers

    // consumer: full pre-activation = sum of 4 wave partials per gate
    float sg[4][2];
#pragma unroll
    for (int g = 0; g < 4; g++) {
      float a = 0.f, b = 0.f;
#pragma unroll
      for (int ww = 0; ww < 4; ww++) {
        a += pre4[ww][g][erow][ecol];
        b += pre4[ww][g][erow][ecol + 1];
      }
      sg[g][0] = a; sg[g][1] = b;
    }
    float i0 = sigm(sg[0][0]), f0 = sigm(sg[1][0]), g0 = tanh_(sg[2][0]), o0 = sigm(sg[3][0]);
    float i1 = sigm(sg[0][1]), f1 = sigm(sg[1][1]), g1 = tanh_(sg[2][1]), o1 = sigm(sg[3][1]);
    cst0 = f0 * cst0 + i0 * g0;
    cst1 = f1 * cst1 + i1 * g1;
    float h0 = o0 * tanh_(cst0);
    float h1 = o1 * tanh_(cst1);
    union { _Float16 h[2]; unsigned int u; } pk;
    pk.h[0] = (_Float16)h0; pk.h[1] = (_Float16)h1;

    if (s == 255) {
      float* hp = hT + (r0 + erow) * 1024 + c0 + ecol;
      hp[0] = h0; hp[1] = h1;
    } else {
      // sc1 write-through store: LLC-visible, bypasses L2
      __hip_atomic_store((unsigned int*)(hnxt + (r0 + erow) * 1024 + c0 + ecol), pk.u,
                         __ATOMIC_RELAXED, __HIP_MEMORY_SCOPE_AGENT);
      // entry: per-wave vmcnt(0) at the barrier drains ONLY h-stores
      // (gx prefetch not yet issued) -> all 4 waves' h-stores LLC-acked.
      __syncthreads();
      // per-BLOCK arrival: one store; issued BEFORE the gx prefetch so no
      // HBM tail can delay it (the R14/R15 flaw).
      if (t == 0)
        __hip_atomic_store(myslot, (unsigned int)(s + 2), __ATOMIC_RELAXED,
                           __HIP_MEMORY_SCOPE_AGENT);
      asm volatile("" ::: "memory");
      // gx prefetch for s+1: after arrival; completes under next poll/h-loads
      {
        const _Float16* gp = gx + (long)(((s + 1) * 4 + w) * 128 + r0) * 1024 + c0 + ln;
#pragma unroll
        for (int mi = 0; mi < 2; mi++)
#pragma unroll
          for (int r = 0; r < 4; r++) nxh[mi][r] = gp[(mi * 16 + q * 4 + r) * 1024];
      }
    }
  }
}

// ---------------- final FC (exact fp32) ----------------
__global__ __launch_bounds__(256) void k_fc(const float* __restrict__ hT, const float* __restrict__ W,
                                            const float* __restrict__ bias, float* __restrict__ out) {
  int gid = blockIdx.x * 4 + (threadIdx.x >> 6);  // wave id < 1280
  int lane = threadIdx.x & 63;
  int b = gid / 10, o = gid - b * 10;
  const float* hp = hT + b * 1024;
  const float* wp = W + o * 1024;
  float sum = 0.f;
  for (int k = lane; k < 1024; k += 64) sum += hp[k] * wp[k];
#pragma unroll
  for (int off = 32; off > 0; off >>= 1) sum += __shfl_down(sum, off, 64);
  if (lane == 0) out[b * 10 + o] = sum + bias[o];
}

// ---------------- launch ----------------
extern "C" void kernel_launch(void* const* d_in, const int* in_sizes, int n_in,
                              void* d_out, int out_size, void* d_ws, size_t ws_size,
                              hipStream_t stream) {
  const int* x = (const int*)d_in[0];
  const float* emb = (const float*)d_in[1];
  const float* Wii = (const float*)d_in[2];
  const float* bii = (const float*)d_in[3];
  const float* Whi = (const float*)d_in[4];
  const float* Wif = (const float*)d_in[5];
  const float* bif = (const float*)d_in[6];
  const float* Whf = (const float*)d_in[7];
  const float* Wig = (const float*)d_in[8];
  const float* big = (const float*)d_in[9];
  const float* Whg = (const float*)d_in[10];
  const float* Wio = (const float*)d_in[11];
  const float* bio = (const float*)d_in[12];
  const float* Who = (const float*)d_in[13];
  const float* fcW = (const float*)d_in[14];
  const float* fcb = (const float*)d_in[15];

  char* ws = (char*)d_ws;
  _Float16* gx = (_Float16*)ws;                    // 268,435,456 B
  _Float16* E = (_Float16*)(ws + 268435456);       // 33,554,432 B (dead after gemm1)
  _Float16* hrot = (_Float16*)(ws + 268435456);    // 4,194,304 B  (16 x 256 KB, overlays E)
  _Float16* WiB = (_Float16*)(ws + 301989888);     // 4,194,304 B
  _Float16* WhB = (_Float16*)(ws + 306184192);     // 8,388,608 B
  float* biasC = (float*)(ws + 314572800);         // 16,384 B
  float* hT = (float*)(ws + 315113472);            // 524,288 B
  unsigned int* bar = (unsigned int*)(ws + 315637760);  // 16,384 B (total ~316 MB)
  float* out = (float*)d_out;

  k_cast_e<<<8192, 256, 0, stream>>>(x, emb, E);
  k_cast_wi<<<1024, 256, 0, stream>>>(Wii, Wif, Wig, Wio, WiB);
  k_cast_wh<<<2048, 256, 0, stream>>>(Whi, Whf, Whg, Who, WhB);
  k_cast_bias<<<16, 256, 0, stream>>>(bii, bif, big, bio, biasC);
  k_gemm1<<<8192, 256, 0, stream>>>(E, WiB, biasC, gx);
  k_zero<<<16, 256, 0, stream>>>(bar);

  const _Float16* gx_a = gx;
  const _Float16* wh_a = WhB;
  _Float16* hb_a = hrot;
  float* ht_a = hT;
  unsigned int* bar_a = bar;
  void* kargs[] = {(void*)&gx_a, (void*)&wh_a, (void*)&hb_a, (void*)&ht_a, (void*)&bar_a};
  hipLaunchCooperativeKernel(k_lstm, dim3(256), dim3(256), kargs, 0, stream);

  k_fc<<<320, 256, 0, stream>>>(hT, fcW, fcb, out);
}